// Round 5
// baseline (314.417 us; speedup 1.0000x reference)
//
#include <hip/hip_runtime.h>
#include <hip/hip_bf16.h>
#include <stdint.h>

// Problem constants
#define NB 2
#define NT 4096
#define NC 768
#define NHEAD 12
#define HS 64
#define MTOK (NB * NT)      // 8192
#define C3 (3 * NC)         // 2304

typedef __bf16 bf16x8 __attribute__((ext_vector_type(8)));
typedef float f32x4 __attribute__((ext_vector_type(4)));
typedef float f32x16 __attribute__((ext_vector_type(16)));

#define KSCALE_LOG2E 0.18033688011f   // (1/sqrt(64)) * log2(e)

__device__ __forceinline__ unsigned short f2bf(float f) {  // RNE
  union { float f; uint32_t u; } v; v.f = f;
  uint32_t r = v.u + 0x7fffu + ((v.u >> 16) & 1u);
  return (unsigned short)(r >> 16);
}
__device__ __forceinline__ unsigned short bft(float f) {   // truncate
  return (unsigned short)(__builtin_bit_cast(unsigned int, f) >> 16);
}
// pack two floats as truncated bf16 pair: low short = a, high short = b
__device__ __forceinline__ uint32_t pack_bf2(float a, float b) {
  return (__builtin_bit_cast(uint32_t, b) & 0xffff0000u) |
         (__builtin_bit_cast(uint32_t, a) >> 16);
}

// async global->LDS, 16B per lane: lane i lands at ldsbase + i*16B.
__device__ __forceinline__ void gload_lds16(const unsigned short* g, unsigned short* ldsbase) {
  __builtin_amdgcn_global_load_lds(
      (const __attribute__((address_space(1))) unsigned int*)g,
      (__attribute__((address_space(3))) unsigned int*)ldsbase, 16, 0, 0);
}

__device__ __forceinline__ f32x4 mfma16(bf16x8 a, bf16x8 b, f32x4 c) {
  return __builtin_amdgcn_mfma_f32_16x16x32_bf16(a, b, c, 0, 0, 0);
}
__device__ __forceinline__ f32x16 mfma32(bf16x8 a, bf16x8 b, f32x16 c) {
  return __builtin_amdgcn_mfma_f32_32x32x16_bf16(a, b, c, 0, 0, 0);
}

// ---------------- prep: coalesced LDS-tiled transposes + x cast ----------------
__global__ __launch_bounds__(256) void prep(
    const float* __restrict__ x, const float* __restrict__ wa, const float* __restrict__ wp,
    unsigned short* __restrict__ xb, unsigned short* __restrict__ waT,
    unsigned short* __restrict__ wpT) {
  const int bx = blockIdx.x;
  if (bx < 576) {
    __shared__ float tile[64][65];
    const float* src; unsigned short* dst;
    int srcN, dstN, k0, n0, qscale;
    if (bx < 432) {
      src = wa; dst = waT; srcN = C3; dstN = NC; qscale = 1;
      k0 = (bx / 36) * 64; n0 = (bx % 36) * 64;
    } else {
      const int t = bx - 432;
      src = wp; dst = wpT; srcN = NC; dstN = NC; qscale = 0;
      k0 = (t / 12) * 64; n0 = (t % 12) * 64;
    }
    const int tr = threadIdx.x >> 4;        // 0..15
    const int tc = (threadIdx.x & 15) * 4;  // 0,4,..,60
#pragma unroll
    for (int p = 0; p < 4; ++p) {
      const int r = p * 16 + tr;
      const float4 v = *reinterpret_cast<const float4*>(src + (size_t)(k0 + r) * srcN + n0 + tc);
      tile[r][tc + 0] = v.x; tile[r][tc + 1] = v.y;
      tile[r][tc + 2] = v.z; tile[r][tc + 3] = v.w;
    }
    __syncthreads();
#pragma unroll
    for (int p = 0; p < 4; ++p) {
      const int n = p * 16 + tr;   // output row = source column n0+n
      const float sc = (qscale && (n0 + n) < NC) ? KSCALE_LOG2E : 1.0f;
      ushort4 o;
      o.x = f2bf(tile[tc + 0][n] * sc); o.y = f2bf(tile[tc + 1][n] * sc);
      o.z = f2bf(tile[tc + 2][n] * sc); o.w = f2bf(tile[tc + 3][n] * sc);
      *reinterpret_cast<ushort4*>(dst + (size_t)(n0 + n) * dstN + k0 + tc) = o;
    }
  } else {
    const int gid = (bx - 576) * 256 + threadIdx.x;   // < MTOK*NC/4
    const float4 v = reinterpret_cast<const float4*>(x)[gid];
    ushort4 o;
    o.x = f2bf(v.x); o.y = f2bf(v.y); o.z = f2bf(v.z); o.w = f2bf(v.w);
    reinterpret_cast<ushort4*>(xb)[gid] = o;
  }
}

// ---------------- GEMM 128x128: C[M,N] = A[M,K] @ Bt[N,K]^T ----------------
// OUT_BF16=1 (gemm1): blocks with col0 >= 2*NC hold the V tile -> transpose
// in-block via smem (16B-chunk XOR swizzle) and write straight to vT
// [B*NH][HS][T]; qkvb's V slice is never written. Other blocks write qkvb rows.
template <int OUT_BF16>
__global__ __launch_bounds__(256) void gemm128(
    const unsigned short* __restrict__ A,   // [M][K]
    const unsigned short* __restrict__ Bt,  // [N][K]
    void* __restrict__ Cout,
    unsigned short* __restrict__ vT,        // used only by OUT_BF16 V-blocks
    int M, int N, int K) {
  __shared__ unsigned short smem[2 * 128 * 64];
  unsigned short* As = smem;
  unsigned short* Bs = smem + 128 * 64;

  const int tid = threadIdx.x;
  const int wave = tid >> 6;
  const int lane = tid & 63;
  const int li = lane & 15;
  const int lq = lane >> 4;
  const int wm = wave & 1;
  const int wn = wave >> 1;
  const int row0 = blockIdx.y * 128;
  const int col0 = blockIdx.x * 128;

  const int crow = lane >> 3;
  const int cchunk = ((lane & 7) ^ crow) * 8;

  f32x4 acc[4][4] = {};

  for (int k0 = 0; k0 < K; k0 += 64) {
#pragma unroll
    for (int i = 0; i < 4; ++i) {
      const int R = wave * 32 + i * 8;
      gload_lds16(A + (size_t)(row0 + R + crow) * K + k0 + cchunk, &As[R * 64]);
      gload_lds16(Bt + (size_t)(col0 + R + crow) * K + k0 + cchunk, &Bs[R * 64]);
    }
    __syncthreads();

#pragma unroll
    for (int ks = 0; ks < 2; ++ks) {
      bf16x8 af[4], bf[4];
#pragma unroll
      for (int f = 0; f < 4; ++f) {
        const int arow = wm * 64 + f * 16 + li;
        af[f] = *reinterpret_cast<const bf16x8*>(&As[arow * 64 + (((ks * 4 + lq) ^ (li & 7)) << 3)]);
        const int brow = wn * 64 + f * 16 + li;
        bf[f] = *reinterpret_cast<const bf16x8*>(&Bs[brow * 64 + (((ks * 4 + lq) ^ (li & 7)) << 3)]);
      }
#pragma unroll
      for (int fa = 0; fa < 4; ++fa)
#pragma unroll
        for (int fb = 0; fb < 4; ++fb)
          acc[fa][fb] = mfma16(af[fa], bf[fb], acc[fa][fb]);
    }
    __syncthreads();   // also protects smem reuse in the fused epilogue
  }

  if (OUT_BF16) {
    if (col0 >= 2 * NC) {
      // ---- fused V transpose: acc -> smem[c][t] -> vT[bh][d][t] ----
      const int b = row0 >> 12;            // row0 / NT
      const int t0r = row0 & (NT - 1);
      const int h0 = (col0 - 2 * NC) >> 6;
      // write phase: value at (c = head-col, t = token) with 16B-chunk XOR swizzle
#pragma unroll
      for (int fa = 0; fa < 4; ++fa) {
#pragma unroll
        for (int fb = 0; fb < 4; ++fb) {
          const int cc = wn * 64 + fb * 16 + li;
#pragma unroll
          for (int r = 0; r < 4; ++r) {
            const int tt = wm * 64 + fa * 16 + lq * 4 + r;
            const int slot = cc * 16 + ((tt >> 3) ^ (cc & 15));
            smem[slot * 8 + (tt & 7)] = f2bf(acc[fa][fb][r]);
          }
        }
      }
      __syncthreads();
      // read phase: 16 lanes cover one c-row's 16 chunks -> 256B coalesced stores
      const int ch = tid & 15;
#pragma unroll
      for (int j = 0; j < 8; ++j) {
        const int cc = (tid >> 4) + 16 * j;
        const uint4 v = *reinterpret_cast<const uint4*>(
            smem + (size_t)(cc * 16 + (ch ^ (cc & 15))) * 8);
        const int bh = b * NHEAD + h0 + (cc >> 6);
        const int d = cc & 63;
        *reinterpret_cast<uint4*>(vT + (size_t)bh * HS * NT + (size_t)d * NT + t0r + ch * 8) = v;
      }
    } else {
      unsigned short* Cb = (unsigned short*)Cout;
#pragma unroll
      for (int fa = 0; fa < 4; ++fa) {
        const int gr = row0 + wm * 64 + fa * 16 + lq * 4;
#pragma unroll
        for (int fb = 0; fb < 4; ++fb) {
          const int gc = col0 + wn * 64 + fb * 16 + li;
#pragma unroll
          for (int r = 0; r < 4; ++r)
            Cb[(size_t)(gr + r) * N + gc] = f2bf(acc[fa][fb][r]);
        }
      }
    }
  } else {
    float* Cf = (float*)Cout;
#pragma unroll
    for (int fa = 0; fa < 4; ++fa) {
      const int gr = row0 + wm * 64 + fa * 16 + lq * 4;
#pragma unroll
      for (int fb = 0; fb < 4; ++fb) {
        const int gc = col0 + wn * 64 + fb * 16 + li;
#pragma unroll
        for (int r = 0; r < 4; ++r)
          Cf[(size_t)(gr + r) * N + gc] = acc[fa][fb][r];
      }
    }
  }
}

// ---------------- Flash attention: persistent 8-wave workers + XCD work stealing ----
// Block = 512 threads (8 waves x 32 q-rows = 256-q super-tile). 48KB LDS 3-deep
// K/V pipeline shared by 8 waves -> 3 blocks/CU = 24 waves/CU static.
// Grid = 768 persistent workers; worker's queue = blockIdx.x & 7 (XCD locality
// heuristic); per-XCD queue = 3 (b,h) groups x 46 LPT-ordered items (quarters
// for qj>=8, halves for 2<=qj<=7, wholes below; max item 16 tiles).
// Splits (qj>=2) accumulate via fp32 atomics into Oacc/lacc (finalize covers
// t>=512); wholes normalize in-register and store bf16 directly.
// Inner tile loop unchanged from R4: counted vmcnt (per-wave 2 loads/tile ->
// vmcnt(2)), one s_barrier/tile, swapped 32x32 QK^T, in-register exp/pack/
// permlane P, l row-sums on the MFMA pipe.

__device__ const uint8_t g_items[46] = {
  15,31,47,63, 7,23, 14,30,46,62, 13,29,45,61, 6,22, 12,28,44,60,
  11,27,43,59, 5,21, 10,26,42,58, 9,25,41,57, 4,20, 8,24,40,56,
  3,19, 1, 2,18, 0};
#define ITEMS_PER_XCD (3 * 46)   // 138

__global__ __launch_bounds__(512) void attn(
    const unsigned short* __restrict__ qkv,   // [B][T][3C] (V slice unused)
    const unsigned short* __restrict__ vT,    // [B*NH][HS][T]
    float* __restrict__ Oacc,                 // [MTOK][NC] fp32, zeroed (split rows)
    float* __restrict__ lacc,                 // [B*NH][NT]  fp32, zeroed
    unsigned int* __restrict__ ctr,           // [8] work counters, zeroed
    unsigned short* __restrict__ aob) {       // [MTOK][NC] bf16 out (direct rows)
  __shared__ unsigned short Ks[3][64 * 64];
  __shared__ unsigned short Vts[3][64 * 64];
  __shared__ unsigned int s_w;

  const int tid = threadIdx.x;
  const int wave = tid >> 6;                  // 0..7
  const int lane = tid & 63;
  const int l31 = lane & 31;
  const int lh = lane >> 5;
  const int sw = l31 & 7;                     // XOR-swizzle key for frag reads
  const int xcd = (int)blockIdx.x & 7;

  // staging geometry: per wave 1 K-call + 1 V-call per tile (8 rows each).
  // DMA dest linear; XOR swizzle applied on the per-lane GLOBAL address:
  // LDS[R][c] = G[R][c ^ (R&7)] with R&7 == lane>>3 here.
  const int grow = lane >> 3;
  const int gch = (lane & 7) ^ grow;
  const int wr = wave * 8;

  bf16x8 vones;
#pragma unroll
  for (int i = 0; i < 8; ++i) vones[i] = (__bf16)1.0f;

#define STAGE(TAU, BUFI)                                                        \
  do {                                                                          \
    const int t0s_ = (TAU) * 64;                                                \
    gload_lds16(kq + (size_t)(t0s_ + wr + grow) * C3 + gch * 8,                 \
                &Ks[BUFI][wr * 64]);                                            \
    gload_lds16(vbase + (size_t)(wr + grow) * NT + t0s_ + gch * 8,              \
                &Vts[BUFI][wr * 64]);                                           \
  } while (0)

#define EXP_PACK(ST, KBLK, DOMASK)                                             \
  do {                                                                         \
    const int kb_ = t0 + (KBLK) * 32 + 4 * lh;                                 \
    float p_[16];                                                              \
    _Pragma("unroll") for (int r = 0; r < 16; ++r) {                           \
      float v_ = (ST)[r];                                                      \
      if (DOMASK) {                                                            \
        const int kt_ = kb_ + (r & 3) + 8 * (r >> 2);                          \
        if (kt_ > qtok) v_ = -INFINITY;                                        \
      }                                                                        \
      p_[r] = __builtin_amdgcn_exp2f(v_);                                      \
    }                                                                          \
    _Pragma("unroll") for (int s = 0; s < 2; ++s) {                            \
      uint32_t a_ = pack_bf2(p_[8 * s + 0], p_[8 * s + 1]);                    \
      uint32_t b_ = pack_bf2(p_[8 * s + 2], p_[8 * s + 3]);                    \
      uint32_t c_ = pack_bf2(p_[8 * s + 4], p_[8 * s + 5]);                    \
      uint32_t d_ = pack_bf2(p_[8 * s + 6], p_[8 * s + 7]);                    \
      asm("v_permlane32_swap_b32 %0, %1" : "+v"(a_), "+v"(c_));                \
      asm("v_permlane32_swap_b32 %0, %1" : "+v"(b_), "+v"(d_));                \
      union { uint32_t u[4]; bf16x8 v8; } pu_;                                 \
      pu_.u[0] = a_; pu_.u[1] = b_; pu_.u[2] = c_; pu_.u[3] = d_;              \
      pa[2 * (KBLK) + s] = pu_.v8;                                             \
    }                                                                          \
  } while (0)

#define PV_STEP(KS)                                                            \
  do {                                                                         \
    const int off_ = ((((KS) * 2 + lh) ^ sw) << 3);                            \
    const bf16x8 bv0_ =                                                        \
        *reinterpret_cast<const bf16x8*>(Vc + (size_t)l31 * 64 + off_);        \
    const bf16x8 bv1_ =                                                        \
        *reinterpret_cast<const bf16x8*>(Vc + (size_t)(32 + l31) * 64 + off_); \
    la = mfma32(pa[KS], vones, la);                                            \
    o0 = mfma32(pa[KS], bv0_, o0);                                             \
    o1 = mfma32(pa[KS], bv1_, o1);                                             \
  } while (0)

  for (;;) {
    __syncthreads();                      // prior item's LDS reads done; s_w free
    if (tid == 0) s_w = atomicAdd(&ctr[xcd], 1u);
    __syncthreads();
    const unsigned int w = s_w;
    if (w >= (unsigned int)ITEMS_PER_XCD) break;

    // ---- item decode ----
    const int grp = xcd * 3 + (int)(w % 3u);      // b*12+h
    const int e = (int)g_items[w / 3u];
    const int qj = e & 15;
    const int part = e >> 4;
    const int ntile = 4 * qj + 4;
    int tauS, tauE;
    if (qj >= 8)      { const int s4 = ntile >> 2; tauS = part * s4; tauE = tauS + s4; }
    else if (qj >= 2) { const int s2 = ntile >> 1; tauS = part * s2; tauE = tauS + s2; }
    else              { tauS = 0; tauE = ntile; }
    const int split = (qj >= 2);
    const int b = grp / 12;
    const int h = grp - b * 12;
    const int bh = grp;
    const int q0 = qj * 256;

    const size_t baseQ = (size_t)b * NT * C3 + (size_t)h * HS;
    const unsigned short* kq = qkv + baseQ + NC;
    const unsigned short* vbase = vT + (size_t)bh * HS * NT;

    const int qw = q0 + wave * 32;          // wave's first q row
    const int qtok = qw + l31;

    // Q B-fragments (pre-scaled via waT)
    bf16x8 bq[4];
#pragma unroll
    for (int ks = 0; ks < 4; ++ks)
      bq[ks] = *reinterpret_cast<const bf16x8*>(
          qkv + baseQ + (size_t)(qw + l31) * C3 + ks * 16 + lh * 8);

    f32x16 o0 = {}, o1 = {}, la = {};

    // prologue: 2 tiles in flight (every item has >= 2 tiles)
    STAGE(tauS, 0);
    STAGE(tauS + 1, 1);

    int cur = 0;
    for (int tau = tauS; tau < tauE; ++tau) {
      const int t0 = tau * 64;
      // counted drain: tile tau's 2 loads landed; tau+1's stay in flight.
      if (tau + 1 < tauE) asm volatile("s_waitcnt vmcnt(2)" ::: "memory");
      else                asm volatile("s_waitcnt vmcnt(0)" ::: "memory");
      __builtin_amdgcn_s_barrier();          // publish buf[cur] to all waves
      __builtin_amdgcn_sched_barrier(0);     // no hoisting across the barrier
      if (tau + 2 < tauE) {
        int nb = cur + 2; if (nb >= 3) nb -= 3;   // overwrites buf read at tau-1
        STAGE(tau + 2, nb);
      }

      const unsigned short* Kc = Ks[cur];
      const unsigned short* Vc = Vts[cur];

      if (t0 <= qw + 31) {                 // wave has live q-rows in this tile
        const bool act1 = (t0 + 32 <= qw + 31);   // k-block 1 live?
        const bool m0 = (t0 + 31 > qw);           // k-block 0 needs masking?
        const bool m1 = (t0 + 63 > qw);           // k-block 1 needs masking?

        // ---- S^T = K Q^T: A = K rows (k-tokens), B = Q cols ----
        f32x16 st0 = {}, st1 = {};
        __builtin_amdgcn_s_setprio(1);
#pragma unroll
        for (int ks = 0; ks < 4; ++ks) {
          const bf16x8 ka = *reinterpret_cast<const bf16x8*>(
              Kc + (size_t)l31 * 64 + (((ks * 2 + lh) ^ sw) << 3));
          st0 = mfma32(ka, bq[ks], st0);
        }
        if (act1) {
#pragma unroll
          for (int ks = 0; ks < 4; ++ks) {
            const bf16x8 ka = *reinterpret_cast<const bf16x8*>(
                Kc + (size_t)(32 + l31) * 64 + (((ks * 2 + lh) ^ sw) << 3));
            st1 = mfma32(ka, bq[ks], st1);
          }
        }
        __builtin_amdgcn_s_setprio(0);

        // ---- exp + pack + swap -> pa[4] (in-register P, bf16 truncate) ----
        bf16x8 pa[4];
        EXP_PACK(st0, 0, m0);
        if (act1) EXP_PACK(st1, 1, m1);

        // ---- O += P V ; l += P . ones (MFMA pipe) ----
        __builtin_amdgcn_s_setprio(1);
        PV_STEP(0); PV_STEP(1);
        if (act1) { PV_STEP(2); PV_STEP(3); }
        __builtin_amdgcn_s_setprio(0);
      }
      ++cur; if (cur == 3) cur = 0;
    }

    // ---- epilogue ----
    // o0/o1 C-layout: col = l31 (d), reg r -> q = qw + (r&3)+8*(r>>2)+4*lh.
    // la[r] = row-sum, uniform across l31.
    if (split) {
      const size_t obase = (size_t)b * NT * NC + (size_t)h * HS;
      float* lrow = lacc + (size_t)bh * NT;
#pragma unroll
      for (int r = 0; r < 16; ++r) {
        const int q = qw + (r & 3) + 8 * (r >> 2) + 4 * lh;
        if (l31 == 0) atomicAdd(&lrow[q], la[r]);
        atomicAdd(&Oacc[obase + (size_t)q * NC + l31], o0[r]);
        atomicAdd(&Oacc[obase + (size_t)q * NC + 32 + l31], o1[r]);
      }
    } else {
#pragma unroll
      for (int r = 0; r < 16; ++r) {
        const int q = qw + (r & 3) + 8 * (r >> 2) + 4 * lh;
        const float inv = 1.0f / la[r];
        unsigned short* orow = aob + ((size_t)b * NT + q) * NC + h * HS;
        orow[l31] = bft(o0[r] * inv);
        orow[32 + l31] = bft(o1[r] * inv);
      }
    }
  }
#undef STAGE
#undef EXP_PACK
#undef PV_STEP
}

// ---------------- finalize: aob = bf16(Oacc / l) for split rows (t >= 512) ----
__global__ __launch_bounds__(256) void finalize(
    const float* __restrict__ Oacc, const float* __restrict__ lacc,
    unsigned short* __restrict__ aob) {
  const int idx4 = (blockIdx.x * 256 + threadIdx.x);
  if (idx4 >= NB * (NT - 512) * NC / 4) return;
  const int idx = idx4 * 4;
  const int rowp = idx / NC;          // 0 .. NB*3584-1
  const int cc = idx - rowp * NC;
  const int b = (rowp >= (NT - 512)) ? 1 : 0;
  const int t = 512 + rowp - b * (NT - 512);
  const int h = cc >> 6;
  const float inv = 1.0f / lacc[(size_t)(b * NHEAD + h) * NT + t];
  const size_t base = ((size_t)b * NT + t) * NC + cc;
  const float4 v = *reinterpret_cast<const float4*>(Oacc + base);
  ushort4 o;
  o.x = bft(v.x * inv); o.y = bft(v.y * inv);
  o.z = bft(v.z * inv); o.w = bft(v.w * inv);
  *reinterpret_cast<ushort4*>(aob + base) = o;
}

// ---------------- launch ----------------
extern "C" void kernel_launch(void* const* d_in, const int* in_sizes, int n_in,
                              void* d_out, int out_size, void* d_ws, size_t ws_size,
                              hipStream_t stream) {
  const float* x = (const float*)d_in[0];       // [B,T,C]
  const float* w_attn = (const float*)d_in[1];  // [C, 3C]
  const float* w_proj = (const float*)d_in[2];  // [C, C]
  float* outp = (float*)d_out;

  // ws layout (Oacc aliases xb/waT, which die after gemm1):
  char* w = (char*)d_ws;
  float* Oacc = (float*)w;
  unsigned short* xb = (unsigned short*)w;                       // aliases Oacc (pre-attn)
  unsigned short* waT = xb + (size_t)MTOK * NC;                  // aliases Oacc tail
  float* lacc = Oacc + (size_t)MTOK * NC;
  unsigned int* ctr = (unsigned int*)(lacc + (size_t)NB * NHEAD * NT);  // 16 slots (8 used)
  unsigned short* qkvb = (unsigned short*)(ctr + 16);
  unsigned short* aob  = qkvb + (size_t)MTOK * C3;               // [MTOK][NC] bf16
  unsigned short* vTb  = aob + (size_t)MTOK * NC;                // [B*NH][HS][T]
  unsigned short* wpT  = vTb + (size_t)MTOK * NC;                // [NC][NC] bf16

  // prep: 576 transpose tiles + x-cast blocks
  prep<<<576 + MTOK * NC / 4 / 256, 256, 0, stream>>>(x, w_attn, w_proj, xb, waT, wpT);

  // qkv = x @ w_attn (Q rows of waT pre-scaled); V blocks write vTb directly
  gemm128<1><<<dim3(C3 / 128, MTOK / 128), 256, 0, stream>>>(xb, waT, qkvb, vTb, MTOK, C3, NC);

  // zero partial accumulators + work counters (xb/waT now dead)
  hipMemsetAsync(Oacc, 0,
      ((size_t)MTOK * NC + (size_t)NB * NHEAD * NT) * sizeof(float) + 16 * sizeof(unsigned int),
      stream);

  // attention: 768 persistent 8-wave workers, per-XCD LPT work stealing
  attn<<<768, 512, 0, stream>>>(qkvb, vTb, Oacc, lacc, ctr, aob);

  // normalize split rows (t >= 512) -> bf16 aob
  finalize<<<(NB * (NT - 512) * NC / 4 + 255) / 256, 256, 0, stream>>>(Oacc, lacc, aob);

  // out = att_out @ w_proj -> fp32 d_out
  gemm128<0><<<dim3(NC / 128, MTOK / 128), 256, 0, stream>>>(aob, wpT, outp, nullptr, MTOK, NC, NC);
}

// Round 6
// 252.837 us; speedup vs baseline: 1.2436x; 1.2436x over previous
//
#include <hip/hip_runtime.h>
#include <hip/hip_bf16.h>
#include <stdint.h>

// Problem constants
#define NB 2
#define NT 4096
#define NC 768
#define NHEAD 12
#define HS 64
#define MTOK (NB * NT)      // 8192
#define C3 (3 * NC)         // 2304

typedef __bf16 bf16x8 __attribute__((ext_vector_type(8)));
typedef float f32x4 __attribute__((ext_vector_type(4)));
typedef float f32x16 __attribute__((ext_vector_type(16)));

#define KSCALE_LOG2E 0.18033688011f   // (1/sqrt(64)) * log2(e)

__device__ __forceinline__ unsigned short f2bf(float f) {  // RNE
  union { float f; uint32_t u; } v; v.f = f;
  uint32_t r = v.u + 0x7fffu + ((v.u >> 16) & 1u);
  return (unsigned short)(r >> 16);
}
__device__ __forceinline__ unsigned short bft(float f) {   // truncate
  return (unsigned short)(__builtin_bit_cast(unsigned int, f) >> 16);
}
// pack two floats as truncated bf16 pair: low short = a, high short = b
__device__ __forceinline__ uint32_t pack_bf2(float a, float b) {
  return (__builtin_bit_cast(uint32_t, b) & 0xffff0000u) |
         (__builtin_bit_cast(uint32_t, a) >> 16);
}

// async global->LDS, 16B per lane: lane i lands at ldsbase + i*16B.
__device__ __forceinline__ void gload_lds16(const unsigned short* g, unsigned short* ldsbase) {
  __builtin_amdgcn_global_load_lds(
      (const __attribute__((address_space(1))) unsigned int*)g,
      (__attribute__((address_space(3))) unsigned int*)ldsbase, 16, 0, 0);
}

__device__ __forceinline__ f32x4 mfma16(bf16x8 a, bf16x8 b, f32x4 c) {
  return __builtin_amdgcn_mfma_f32_16x16x32_bf16(a, b, c, 0, 0, 0);
}
__device__ __forceinline__ f32x16 mfma32(bf16x8 a, bf16x8 b, f32x16 c) {
  return __builtin_amdgcn_mfma_f32_32x32x16_bf16(a, b, c, 0, 0, 0);
}

// ---------------- prep: coalesced LDS-tiled transposes + x cast ----------------
__global__ __launch_bounds__(256) void prep(
    const float* __restrict__ x, const float* __restrict__ wa, const float* __restrict__ wp,
    unsigned short* __restrict__ xb, unsigned short* __restrict__ waT,
    unsigned short* __restrict__ wpT) {
  const int bx = blockIdx.x;
  if (bx < 576) {
    __shared__ float tile[64][65];
    const float* src; unsigned short* dst;
    int srcN, dstN, k0, n0, qscale;
    if (bx < 432) {
      src = wa; dst = waT; srcN = C3; dstN = NC; qscale = 1;
      k0 = (bx / 36) * 64; n0 = (bx % 36) * 64;
    } else {
      const int t = bx - 432;
      src = wp; dst = wpT; srcN = NC; dstN = NC; qscale = 0;
      k0 = (t / 12) * 64; n0 = (t % 12) * 64;
    }
    const int tr = threadIdx.x >> 4;        // 0..15
    const int tc = (threadIdx.x & 15) * 4;  // 0,4,..,60
#pragma unroll
    for (int p = 0; p < 4; ++p) {
      const int r = p * 16 + tr;
      const float4 v = *reinterpret_cast<const float4*>(src + (size_t)(k0 + r) * srcN + n0 + tc);
      tile[r][tc + 0] = v.x; tile[r][tc + 1] = v.y;
      tile[r][tc + 2] = v.z; tile[r][tc + 3] = v.w;
    }
    __syncthreads();
#pragma unroll
    for (int p = 0; p < 4; ++p) {
      const int n = p * 16 + tr;   // output row = source column n0+n
      const float sc = (qscale && (n0 + n) < NC) ? KSCALE_LOG2E : 1.0f;
      ushort4 o;
      o.x = f2bf(tile[tc + 0][n] * sc); o.y = f2bf(tile[tc + 1][n] * sc);
      o.z = f2bf(tile[tc + 2][n] * sc); o.w = f2bf(tile[tc + 3][n] * sc);
      *reinterpret_cast<ushort4*>(dst + (size_t)(n0 + n) * dstN + k0 + tc) = o;
    }
  } else {
    const int gid = (bx - 576) * 256 + threadIdx.x;   // < MTOK*NC/4
    const float4 v = reinterpret_cast<const float4*>(x)[gid];
    ushort4 o;
    o.x = f2bf(v.x); o.y = f2bf(v.y); o.z = f2bf(v.z); o.w = f2bf(v.w);
    reinterpret_cast<ushort4*>(xb)[gid] = o;
  }
}

// ---------------- GEMM 128x128: C[M,N] = A[M,K] @ Bt[N,K]^T ----------------
// OUT_BF16=1 (gemm1): blocks with col0 >= 2*NC hold the V tile -> transpose
// in-block via smem (16B-chunk XOR swizzle) and write straight to vT
// [B*NH][HS][T]; qkvb's V slice is never written. Other blocks write qkvb rows.
template <int OUT_BF16>
__global__ __launch_bounds__(256) void gemm128(
    const unsigned short* __restrict__ A,   // [M][K]
    const unsigned short* __restrict__ Bt,  // [N][K]
    void* __restrict__ Cout,
    unsigned short* __restrict__ vT,        // used only by OUT_BF16 V-blocks
    int M, int N, int K) {
  __shared__ unsigned short smem[2 * 128 * 64];
  unsigned short* As = smem;
  unsigned short* Bs = smem + 128 * 64;

  const int tid = threadIdx.x;
  const int wave = tid >> 6;
  const int lane = tid & 63;
  const int li = lane & 15;
  const int lq = lane >> 4;
  const int wm = wave & 1;
  const int wn = wave >> 1;
  const int row0 = blockIdx.y * 128;
  const int col0 = blockIdx.x * 128;

  const int crow = lane >> 3;
  const int cchunk = ((lane & 7) ^ crow) * 8;

  f32x4 acc[4][4] = {};

  for (int k0 = 0; k0 < K; k0 += 64) {
#pragma unroll
    for (int i = 0; i < 4; ++i) {
      const int R = wave * 32 + i * 8;
      gload_lds16(A + (size_t)(row0 + R + crow) * K + k0 + cchunk, &As[R * 64]);
      gload_lds16(Bt + (size_t)(col0 + R + crow) * K + k0 + cchunk, &Bs[R * 64]);
    }
    __syncthreads();

#pragma unroll
    for (int ks = 0; ks < 2; ++ks) {
      bf16x8 af[4], bf[4];
#pragma unroll
      for (int f = 0; f < 4; ++f) {
        const int arow = wm * 64 + f * 16 + li;
        af[f] = *reinterpret_cast<const bf16x8*>(&As[arow * 64 + (((ks * 4 + lq) ^ (li & 7)) << 3)]);
        const int brow = wn * 64 + f * 16 + li;
        bf[f] = *reinterpret_cast<const bf16x8*>(&Bs[brow * 64 + (((ks * 4 + lq) ^ (li & 7)) << 3)]);
      }
#pragma unroll
      for (int fa = 0; fa < 4; ++fa)
#pragma unroll
        for (int fb = 0; fb < 4; ++fb)
          acc[fa][fb] = mfma16(af[fa], bf[fb], acc[fa][fb]);
    }
    __syncthreads();   // also protects smem reuse in the fused epilogue
  }

  if (OUT_BF16) {
    if (col0 >= 2 * NC) {
      // ---- fused V transpose: acc -> smem[c][t] -> vT[bh][d][t] ----
      const int b = row0 >> 12;            // row0 / NT
      const int t0r = row0 & (NT - 1);
      const int h0 = (col0 - 2 * NC) >> 6;
      // write phase: value at (c = head-col, t = token) with 16B-chunk XOR swizzle
#pragma unroll
      for (int fa = 0; fa < 4; ++fa) {
#pragma unroll
        for (int fb = 0; fb < 4; ++fb) {
          const int cc = wn * 64 + fb * 16 + li;
#pragma unroll
          for (int r = 0; r < 4; ++r) {
            const int tt = wm * 64 + fa * 16 + lq * 4 + r;
            const int slot = cc * 16 + ((tt >> 3) ^ (cc & 15));
            smem[slot * 8 + (tt & 7)] = f2bf(acc[fa][fb][r]);
          }
        }
      }
      __syncthreads();
      // read phase: 16 lanes cover one c-row's 16 chunks -> 256B coalesced stores
      const int ch = tid & 15;
#pragma unroll
      for (int j = 0; j < 8; ++j) {
        const int cc = (tid >> 4) + 16 * j;
        const uint4 v = *reinterpret_cast<const uint4*>(
            smem + (size_t)(cc * 16 + (ch ^ (cc & 15))) * 8);
        const int bh = b * NHEAD + h0 + (cc >> 6);
        const int d = cc & 63;
        *reinterpret_cast<uint4*>(vT + (size_t)bh * HS * NT + (size_t)d * NT + t0r + ch * 8) = v;
      }
    } else {
      unsigned short* Cb = (unsigned short*)Cout;
#pragma unroll
      for (int fa = 0; fa < 4; ++fa) {
        const int gr = row0 + wm * 64 + fa * 16 + lq * 4;
#pragma unroll
        for (int fb = 0; fb < 4; ++fb) {
          const int gc = col0 + wn * 64 + fb * 16 + li;
#pragma unroll
          for (int r = 0; r < 4; ++r)
            Cb[(size_t)(gr + r) * N + gc] = f2bf(acc[fa][fb][r]);
        }
      }
    }
  } else {
    float* Cf = (float*)Cout;
#pragma unroll
    for (int fa = 0; fa < 4; ++fa) {
      const int gr = row0 + wm * 64 + fa * 16 + lq * 4;
#pragma unroll
      for (int fb = 0; fb < 4; ++fb) {
        const int gc = col0 + wn * 64 + fb * 16 + li;
#pragma unroll
        for (int r = 0; r < 4; ++r)
          Cf[(size_t)(gr + r) * N + gc] = acc[fa][fb][r];
      }
    }
  }
}

// ---------------- Flash attention: balanced items, slot stores (NO atomics) ----
// Work items (48 per (b,h), 1152 blocks) — identical geometry to R4:
//   idx  0..31: qi = 31 - idx/2 (>=16), KV range split in equal halves,
//               part = idx&1 -> DETERMINISTIC slot store (no atomics):
//               part0 -> Oacc[b][t]      / lacc[bh][t]
//               part1 -> Oacc[b][t-2048] / lacc[bh][t-2048]
//               (rows t<2048 of Oacc/lacc are unused by the direct path,
//                so slot 1 is free; every slot written exactly once -> no
//                memset, plain coalesced streaming stores.)
//   idx 32..47: qi = 47 - idx (<16), whole triangle -> normalize in-register,
//               store bf16 directly to aob.
// XCD-chunked bijective remap: w = (bid&7)*144 + bid/8 keeps each (b,h)'s 48
// items on one XCD (K/V L2 reuse), largest-first within XCD.
// Inner loop (unchanged from R4): 3-deep LDS buffers, counted vmcnt(4), one
// s_barrier/tile, swapped 32x32 QK^T, in-register exp/pack/permlane P,
// l row-sums on the MFMA pipe.

__global__ __launch_bounds__(256) void attn(
    const unsigned short* __restrict__ qkv,   // [B][T][3C] (V slice unused)
    const unsigned short* __restrict__ vT,    // [B*NH][HS][T]
    float* __restrict__ Oacc,                 // [MTOK][NC] fp32 slot space
    float* __restrict__ lacc,                 // [B*NH][NT]  fp32 slot space
    unsigned short* __restrict__ aob) {       // [MTOK][NC] bf16 out (direct rows)
  __shared__ unsigned short Ks[3][64 * 64];
  __shared__ unsigned short Vts[3][64 * 64];

  const int tid = threadIdx.x;
  const int wave = tid >> 6;
  const int lane = tid & 63;
  const int l31 = lane & 31;
  const int lh = lane >> 5;
  const int sw = l31 & 7;                     // XOR-swizzle key for frag reads

  // ---- work decode (XCD-chunked, bijective: 1152 = 8 * 144) ----
  const int bid = (int)blockIdx.x;
  const int w = (bid & 7) * 144 + (bid >> 3);
  const int grp = w / 48;                     // 0..23 = b*12+h
  const int idx = w - grp * 48;
  const int b = grp / 12;
  const int h = grp - b * 12;
  int qi, tauS, tauE, part, split;
  if (idx < 32) {
    split = 1;
    part = idx & 1;
    qi = 31 - (idx >> 1);                     // 31..16
    const int nt = 2 * qi + 2;
    if (part) { tauS = nt >> 1; tauE = nt; }
    else      { tauS = 0;       tauE = nt >> 1; }
  } else {
    split = 0; part = 0;
    qi = 47 - idx;                            // 15..0
    tauS = 0; tauE = 2 * qi + 2;
  }
  const int q0 = qi * 128;
  const int bh = b * NHEAD + h;

  const size_t baseQ = (size_t)b * NT * C3 + (size_t)h * HS;
  const size_t baseK = baseQ + NC;
  const unsigned short* kq = qkv + baseK;
  const unsigned short* vbase = vT + (size_t)bh * HS * NT;

  const int qw = q0 + wave * 32;              // wave's first q row
  const int qtok = qw + l31;                  // this lane's q token

  // Q B-fragments (pre-scaled via waT): lane holds Q[q=qw+l31][ks*16+lh*8..+7]
  bf16x8 bq[4];
#pragma unroll
  for (int ks = 0; ks < 4; ++ks)
    bq[ks] = *reinterpret_cast<const bf16x8*>(
        qkv + baseQ + (size_t)(qw + l31) * C3 + ks * 16 + lh * 8);

  // all-ones B fragment for l row-sums on the MFMA pipe
  bf16x8 vones;
#pragma unroll
  for (int i = 0; i < 8; ++i) vones[i] = (__bf16)1.0f;

  f32x16 o0 = {}, o1 = {}, la = {};

  // ---- gload staging geometry: per wave, 2 calls x 8 rows for K and V ----
  // DMA writes linear (wave-uniform LDS base + lane*16B); the XOR swizzle is
  // applied on the per-lane GLOBAL address instead: LDS[R][c] = G[R][c^(R&7)].
  const int grow = lane >> 3;               // row within 8-row group
  const int gch = (lane & 7) ^ grow;        // pre-swizzled 16B chunk
  const int wr0 = wave * 8;                 // uniform row bases
  const int wr1 = wave * 8 + 32;

#define STAGE(TAU, BUFI)                                                        \
  do {                                                                          \
    const int t0s_ = (TAU) * 64;                                                \
    gload_lds16(kq + (size_t)(t0s_ + wr0 + grow) * C3 + gch * 8,                \
                &Ks[BUFI][wr0 * 64]);                                           \
    gload_lds16(kq + (size_t)(t0s_ + wr1 + grow) * C3 + gch * 8,                \
                &Ks[BUFI][wr1 * 64]);                                           \
    gload_lds16(vbase + (size_t)(wr0 + grow) * NT + t0s_ + gch * 8,             \
                &Vts[BUFI][wr0 * 64]);                                          \
    gload_lds16(vbase + (size_t)(wr1 + grow) * NT + t0s_ + gch * 8,             \
                &Vts[BUFI][wr1 * 64]);                                          \
  } while (0)

// exp + pack + permlane-swap one 32-k block (16 S^T regs) into pa[2*KBLK+s].
#define EXP_PACK(ST, KBLK, DOMASK)                                             \
  do {                                                                         \
    const int kb_ = t0 + (KBLK) * 32 + 4 * lh;                                 \
    float p_[16];                                                              \
    _Pragma("unroll") for (int r = 0; r < 16; ++r) {                           \
      float v_ = (ST)[r];                                                      \
      if (DOMASK) {                                                            \
        const int kt_ = kb_ + (r & 3) + 8 * (r >> 2);                          \
        if (kt_ > qtok) v_ = -INFINITY;                                        \
      }                                                                        \
      p_[r] = __builtin_amdgcn_exp2f(v_);                                      \
    }                                                                          \
    _Pragma("unroll") for (int s = 0; s < 2; ++s) {                            \
      uint32_t a_ = pack_bf2(p_[8 * s + 0], p_[8 * s + 1]);                    \
      uint32_t b_ = pack_bf2(p_[8 * s + 2], p_[8 * s + 3]);                    \
      uint32_t c_ = pack_bf2(p_[8 * s + 4], p_[8 * s + 5]);                    \
      uint32_t d_ = pack_bf2(p_[8 * s + 6], p_[8 * s + 7]);                    \
      asm("v_permlane32_swap_b32 %0, %1" : "+v"(a_), "+v"(c_));                \
      asm("v_permlane32_swap_b32 %0, %1" : "+v"(b_), "+v"(d_));                \
      union { uint32_t u[4]; bf16x8 v8; } pu_;                                 \
      pu_.u[0] = a_; pu_.u[1] = b_; pu_.u[2] = c_; pu_.u[3] = d_;              \
      pa[2 * (KBLK) + s] = pu_.v8;                                             \
    }                                                                          \
  } while (0)

// one PV k-step (16 k-tokens): l += P.1 ; O += P V  (V B-frag rows = d)
#define PV_STEP(KS)                                                            \
  do {                                                                         \
    const int off_ = ((((KS) * 2 + lh) ^ sw) << 3);                            \
    const bf16x8 bv0_ =                                                        \
        *reinterpret_cast<const bf16x8*>(Vc + (size_t)l31 * 64 + off_);        \
    const bf16x8 bv1_ =                                                        \
        *reinterpret_cast<const bf16x8*>(Vc + (size_t)(32 + l31) * 64 + off_); \
    la = mfma32(pa[KS], vones, la);                                            \
    o0 = mfma32(pa[KS], bv0_, o0);                                             \
    o1 = mfma32(pa[KS], bv1_, o1);                                             \
  } while (0)

  // prologue: 2 tiles in flight (tauE - tauS >= 2 always)
  STAGE(tauS, 0);
  STAGE(tauS + 1, 1);

  int cur = 0;
  for (int tau = tauS; tau < tauE; ++tau) {
    const int t0 = tau * 64;
    // counted drain: tile tau's 4 loads landed; tau+1's stay in flight.
    if (tau + 1 < tauE) asm volatile("s_waitcnt vmcnt(4)" ::: "memory");
    else                asm volatile("s_waitcnt vmcnt(0)" ::: "memory");
    __builtin_amdgcn_s_barrier();          // publish buf[cur] to all waves
    __builtin_amdgcn_sched_barrier(0);     // no hoisting across the barrier
    if (tau + 2 < tauE) {
      int nb = cur + 2; if (nb >= 3) nb -= 3;   // overwrites buf read at tau-1
      STAGE(tau + 2, nb);
    }

    const unsigned short* Kc = Ks[cur];
    const unsigned short* Vc = Vts[cur];

    if (t0 <= qw + 31) {                 // wave has live q-rows in this tile
      const bool act1 = (t0 + 32 <= qw + 31);   // k-block 1 live?
      const bool m0 = (t0 + 31 > qw);           // k-block 0 needs masking?
      const bool m1 = (t0 + 63 > qw);           // k-block 1 needs masking?

      // ---- S^T = K Q^T: A = K rows (k-tokens), B = Q cols ----
      f32x16 st0 = {}, st1 = {};
      __builtin_amdgcn_s_setprio(1);
#pragma unroll
      for (int ks = 0; ks < 4; ++ks) {
        const bf16x8 ka = *reinterpret_cast<const bf16x8*>(
            Kc + (size_t)l31 * 64 + (((ks * 2 + lh) ^ sw) << 3));
        st0 = mfma32(ka, bq[ks], st0);
      }
      if (act1) {
#pragma unroll
        for (int ks = 0; ks < 4; ++ks) {
          const bf16x8 ka = *reinterpret_cast<const bf16x8*>(
              Kc + (size_t)(32 + l31) * 64 + (((ks * 2 + lh) ^ sw) << 3));
          st1 = mfma32(ka, bq[ks], st1);
        }
      }
      __builtin_amdgcn_s_setprio(0);

      // ---- exp + pack + swap -> pa[4] (in-register P, bf16 truncate) ----
      bf16x8 pa[4];
      EXP_PACK(st0, 0, m0);
      if (act1) EXP_PACK(st1, 1, m1);

      // ---- O += P V ; l += P . ones (MFMA pipe) ----
      __builtin_amdgcn_s_setprio(1);
      PV_STEP(0); PV_STEP(1);
      if (act1) { PV_STEP(2); PV_STEP(3); }
      __builtin_amdgcn_s_setprio(0);
    }
    ++cur; if (cur == 3) cur = 0;
  }
#undef STAGE
#undef EXP_PACK
#undef PV_STEP

  // ---- epilogue ----
  // o0/o1 C-layout: col = l31 (d), reg r -> q = qw + (r&3)+8*(r>>2)+4*lh.
  // la[r] = row-sum, uniform across l31.
  if (split) {
    // deterministic slot store (no atomics): slot row = q (part0) or q-2048.
    float* lrow = lacc + (size_t)bh * NT;
#pragma unroll
    for (int r = 0; r < 16; ++r) {
      const int q = qw + (r & 3) + 8 * (r >> 2) + 4 * lh;
      const int srow = part ? (q - 2048) : q;
      if (l31 == 0) lrow[srow] = la[r];
      float* orow = Oacc + ((size_t)b * NT + srow) * NC + h * HS;
      orow[l31] = o0[r];
      orow[32 + l31] = o1[r];
    }
  } else {
#pragma unroll
    for (int r = 0; r < 16; ++r) {
      const int q = qw + (r & 3) + 8 * (r >> 2) + 4 * lh;
      const float inv = 1.0f / la[r];
      unsigned short* orow = aob + ((size_t)b * NT + q) * NC + h * HS;
      orow[l31] = bft(o0[r] * inv);
      orow[32 + l31] = bft(o1[r] * inv);
    }
  }
}

// ---------------- finalize: merge 2 slots, aob = bf16((O0+O1)/(l0+l1)), t >= 2048 ----
__global__ __launch_bounds__(256) void finalize(
    const float* __restrict__ Oacc, const float* __restrict__ lacc,
    unsigned short* __restrict__ aob) {
  const int idx4 = (blockIdx.x * 256 + threadIdx.x);
  if (idx4 >= NB * (NT / 2) * NC / 4) return;
  const int idx = idx4 * 4;
  const int rowp = idx / NC;          // 0 .. NB*2048-1
  const int cc = idx - rowp * NC;
  const int b = rowp >> 11;           // NT/2 = 2048
  const int t = (NT / 2) + (rowp & 2047);
  const int h = cc >> 6;
  const float* lrow = lacc + (size_t)(b * NHEAD + h) * NT;
  const float inv = 1.0f / (lrow[t] + lrow[t - 2048]);
  const size_t base0 = ((size_t)b * NT + t) * NC + cc;
  const size_t base1 = ((size_t)b * NT + (t - 2048)) * NC + cc;
  const float4 v0 = *reinterpret_cast<const float4*>(Oacc + base0);
  const float4 v1 = *reinterpret_cast<const float4*>(Oacc + base1);
  ushort4 o;
  o.x = bft((v0.x + v1.x) * inv); o.y = bft((v0.y + v1.y) * inv);
  o.z = bft((v0.z + v1.z) * inv); o.w = bft((v0.w + v1.w) * inv);
  *reinterpret_cast<ushort4*>(aob + base0) = o;
}

// ---------------- launch ----------------
extern "C" void kernel_launch(void* const* d_in, const int* in_sizes, int n_in,
                              void* d_out, int out_size, void* d_ws, size_t ws_size,
                              hipStream_t stream) {
  const float* x = (const float*)d_in[0];       // [B,T,C]
  const float* w_attn = (const float*)d_in[1];  // [C, 3C]
  const float* w_proj = (const float*)d_in[2];  // [C, C]
  float* outp = (float*)d_out;

  // ws layout (Oacc aliases xb/waT, which die after gemm1; every slot row of
  // Oacc/lacc is written before finalize reads it -> no memset needed):
  char* w = (char*)d_ws;
  float* Oacc = (float*)w;
  unsigned short* xb = (unsigned short*)w;                       // aliases Oacc (pre-attn)
  unsigned short* waT = xb + (size_t)MTOK * NC;                  // aliases Oacc tail
  float* lacc = Oacc + (size_t)MTOK * NC;
  unsigned short* qkvb = (unsigned short*)(lacc + (size_t)NB * NHEAD * NT);
  unsigned short* aob  = qkvb + (size_t)MTOK * C3;               // [MTOK][NC] bf16
  unsigned short* vTb  = aob + (size_t)MTOK * NC;                // [B*NH][HS][T]
  unsigned short* wpT  = vTb + (size_t)MTOK * NC;                // [NC][NC] bf16

  // prep: 576 transpose tiles + x-cast blocks
  prep<<<576 + MTOK * NC / 4 / 256, 256, 0, stream>>>(x, w_attn, w_proj, xb, waT, wpT);

  // qkv = x @ w_attn (Q rows of waT pre-scaled); V blocks write vTb directly
  gemm128<1><<<dim3(C3 / 128, MTOK / 128), 256, 0, stream>>>(xb, waT, qkvb, vTb, MTOK, C3, NC);

  // attention: 1152 balanced items, deterministic slot stores (no atomics/memset)
  attn<<<1152, 256, 0, stream>>>(qkvb, vTb, Oacc, lacc, aob);

  // merge slots + normalize rows t >= 2048 -> bf16 aob
  finalize<<<(NB * (NT / 2) * NC / 4 + 255) / 256, 256, 0, stream>>>(Oacc, lacc, aob);

  // out = att_out @ w_proj -> fp32 d_out
  gemm128<0><<<dim3(NC / 128, MTOK / 128), 256, 0, stream>>>(aob, wpT, outp, nullptr, MTOK, NC, NC);
}

// Round 7
// 242.267 us; speedup vs baseline: 1.2978x; 1.0436x over previous
//
#include <hip/hip_runtime.h>
#include <hip/hip_bf16.h>
#include <stdint.h>

// Problem constants
#define NB 2
#define NT 4096
#define NC 768
#define NHEAD 12
#define HS 64
#define MTOK (NB * NT)      // 8192
#define C3 (3 * NC)         // 2304

typedef __bf16 bf16x8 __attribute__((ext_vector_type(8)));
typedef float f32x4 __attribute__((ext_vector_type(4)));
typedef float f32x16 __attribute__((ext_vector_type(16)));

#define KSCALE_LOG2E 0.18033688011f   // (1/sqrt(64)) * log2(e)

__device__ __forceinline__ unsigned short f2bf(float f) {  // RNE
  union { float f; uint32_t u; } v; v.f = f;
  uint32_t r = v.u + 0x7fffu + ((v.u >> 16) & 1u);
  return (unsigned short)(r >> 16);
}
__device__ __forceinline__ unsigned short bft(float f) {   // truncate
  return (unsigned short)(__builtin_bit_cast(unsigned int, f) >> 16);
}
// pack two floats as truncated bf16 pair via v_perm_b32: D = [a.hi16 | b.hi16<<16]
// pool bytes 0-3 = src1(b), 4-7 = src0(a); sel 0x03020706 -> b0=a.b2,b1=a.b3,b2=b.b2,b3=b.b3
__device__ __forceinline__ uint32_t pack_bf2(float a, float b) {
  return __builtin_amdgcn_perm(__builtin_bit_cast(uint32_t, a),
                               __builtin_bit_cast(uint32_t, b), 0x03020706u);
}

// async global->LDS, 16B per lane: lane i lands at ldsbase + i*16B.
__device__ __forceinline__ void gload_lds16(const unsigned short* g, unsigned short* ldsbase) {
  __builtin_amdgcn_global_load_lds(
      (const __attribute__((address_space(1))) unsigned int*)g,
      (__attribute__((address_space(3))) unsigned int*)ldsbase, 16, 0, 0);
}

__device__ __forceinline__ f32x4 mfma16(bf16x8 a, bf16x8 b, f32x4 c) {
  return __builtin_amdgcn_mfma_f32_16x16x32_bf16(a, b, c, 0, 0, 0);
}
__device__ __forceinline__ f32x16 mfma32(bf16x8 a, bf16x8 b, f32x16 c) {
  return __builtin_amdgcn_mfma_f32_32x32x16_bf16(a, b, c, 0, 0, 0);
}

// ---------------- prep: coalesced LDS-tiled transposes + x cast ----------------
__global__ __launch_bounds__(256) void prep(
    const float* __restrict__ x, const float* __restrict__ wa, const float* __restrict__ wp,
    unsigned short* __restrict__ xb, unsigned short* __restrict__ waT,
    unsigned short* __restrict__ wpT) {
  const int bx = blockIdx.x;
  if (bx < 576) {
    __shared__ float tile[64][65];
    const float* src; unsigned short* dst;
    int srcN, dstN, k0, n0, qscale;
    if (bx < 432) {
      src = wa; dst = waT; srcN = C3; dstN = NC; qscale = 1;
      k0 = (bx / 36) * 64; n0 = (bx % 36) * 64;
    } else {
      const int t = bx - 432;
      src = wp; dst = wpT; srcN = NC; dstN = NC; qscale = 0;
      k0 = (t / 12) * 64; n0 = (t % 12) * 64;
    }
    const int tr = threadIdx.x >> 4;        // 0..15
    const int tc = (threadIdx.x & 15) * 4;  // 0,4,..,60
#pragma unroll
    for (int p = 0; p < 4; ++p) {
      const int r = p * 16 + tr;
      const float4 v = *reinterpret_cast<const float4*>(src + (size_t)(k0 + r) * srcN + n0 + tc);
      tile[r][tc + 0] = v.x; tile[r][tc + 1] = v.y;
      tile[r][tc + 2] = v.z; tile[r][tc + 3] = v.w;
    }
    __syncthreads();
#pragma unroll
    for (int p = 0; p < 4; ++p) {
      const int n = p * 16 + tr;   // output row = source column n0+n
      const float sc = (qscale && (n0 + n) < NC) ? KSCALE_LOG2E : 1.0f;
      ushort4 o;
      o.x = f2bf(tile[tc + 0][n] * sc); o.y = f2bf(tile[tc + 1][n] * sc);
      o.z = f2bf(tile[tc + 2][n] * sc); o.w = f2bf(tile[tc + 3][n] * sc);
      *reinterpret_cast<ushort4*>(dst + (size_t)(n0 + n) * dstN + k0 + tc) = o;
    }
  } else {
    const int gid = (bx - 576) * 256 + threadIdx.x;   // < MTOK*NC/4
    const float4 v = reinterpret_cast<const float4*>(x)[gid];
    ushort4 o;
    o.x = f2bf(v.x); o.y = f2bf(v.y); o.z = f2bf(v.z); o.w = f2bf(v.w);
    reinterpret_cast<ushort4*>(xb)[gid] = o;
  }
}

// ---------------- GEMM 128x128: C[M,N] = A[M,K] @ Bt[N,K]^T ----------------
// OUT_BF16=1 (gemm1): blocks with col0 >= 2*NC hold the V tile -> transpose
// in-block via smem (16B-chunk XOR swizzle) and write straight to vT
// [B*NH][HS][T]; qkvb's V slice is never written. Other blocks write qkvb rows.
template <int OUT_BF16>
__global__ __launch_bounds__(256) void gemm128(
    const unsigned short* __restrict__ A,   // [M][K]
    const unsigned short* __restrict__ Bt,  // [N][K]
    void* __restrict__ Cout,
    unsigned short* __restrict__ vT,        // used only by OUT_BF16 V-blocks
    int M, int N, int K) {
  __shared__ unsigned short smem[2 * 128 * 64];
  unsigned short* As = smem;
  unsigned short* Bs = smem + 128 * 64;

  const int tid = threadIdx.x;
  const int wave = tid >> 6;
  const int lane = tid & 63;
  const int li = lane & 15;
  const int lq = lane >> 4;
  const int wm = wave & 1;
  const int wn = wave >> 1;
  const int row0 = blockIdx.y * 128;
  const int col0 = blockIdx.x * 128;

  const int crow = lane >> 3;
  const int cchunk = ((lane & 7) ^ crow) * 8;

  f32x4 acc[4][4] = {};

  for (int k0 = 0; k0 < K; k0 += 64) {
#pragma unroll
    for (int i = 0; i < 4; ++i) {
      const int R = wave * 32 + i * 8;
      gload_lds16(A + (size_t)(row0 + R + crow) * K + k0 + cchunk, &As[R * 64]);
      gload_lds16(Bt + (size_t)(col0 + R + crow) * K + k0 + cchunk, &Bs[R * 64]);
    }
    __syncthreads();

#pragma unroll
    for (int ks = 0; ks < 2; ++ks) {
      bf16x8 af[4], bf[4];
#pragma unroll
      for (int f = 0; f < 4; ++f) {
        const int arow = wm * 64 + f * 16 + li;
        af[f] = *reinterpret_cast<const bf16x8*>(&As[arow * 64 + (((ks * 4 + lq) ^ (li & 7)) << 3)]);
        const int brow = wn * 64 + f * 16 + li;
        bf[f] = *reinterpret_cast<const bf16x8*>(&Bs[brow * 64 + (((ks * 4 + lq) ^ (li & 7)) << 3)]);
      }
#pragma unroll
      for (int fa = 0; fa < 4; ++fa)
#pragma unroll
        for (int fb = 0; fb < 4; ++fb)
          acc[fa][fb] = mfma16(af[fa], bf[fb], acc[fa][fb]);
    }
    __syncthreads();   // also protects smem reuse in the fused epilogue
  }

  if (OUT_BF16) {
    if (col0 >= 2 * NC) {
      // ---- fused V transpose: acc -> smem[c][t] -> vT[bh][d][t] ----
      const int b = row0 >> 12;            // row0 / NT
      const int t0r = row0 & (NT - 1);
      const int h0 = (col0 - 2 * NC) >> 6;
      // write phase: value at (c = head-col, t = token) with 16B-chunk XOR swizzle
#pragma unroll
      for (int fa = 0; fa < 4; ++fa) {
#pragma unroll
        for (int fb = 0; fb < 4; ++fb) {
          const int cc = wn * 64 + fb * 16 + li;
#pragma unroll
          for (int r = 0; r < 4; ++r) {
            const int tt = wm * 64 + fa * 16 + lq * 4 + r;
            const int slot = cc * 16 + ((tt >> 3) ^ (cc & 15));
            smem[slot * 8 + (tt & 7)] = f2bf(acc[fa][fb][r]);
          }
        }
      }
      __syncthreads();
      // read phase: 16 lanes cover one c-row's 16 chunks -> 256B coalesced stores
      const int ch = tid & 15;
#pragma unroll
      for (int j = 0; j < 8; ++j) {
        const int cc = (tid >> 4) + 16 * j;
        const uint4 v = *reinterpret_cast<const uint4*>(
            smem + (size_t)(cc * 16 + (ch ^ (cc & 15))) * 8);
        const int bh = b * NHEAD + h0 + (cc >> 6);
        const int d = cc & 63;
        *reinterpret_cast<uint4*>(vT + (size_t)bh * HS * NT + (size_t)d * NT + t0r + ch * 8) = v;
      }
    } else {
      unsigned short* Cb = (unsigned short*)Cout;
#pragma unroll
      for (int fa = 0; fa < 4; ++fa) {
        const int gr = row0 + wm * 64 + fa * 16 + lq * 4;
#pragma unroll
        for (int fb = 0; fb < 4; ++fb) {
          const int gc = col0 + wn * 64 + fb * 16 + li;
#pragma unroll
          for (int r = 0; r < 4; ++r)
            Cb[(size_t)(gr + r) * N + gc] = f2bf(acc[fa][fb][r]);
        }
      }
    }
  } else {
    float* Cf = (float*)Cout;
#pragma unroll
    for (int fa = 0; fa < 4; ++fa) {
      const int gr = row0 + wm * 64 + fa * 16 + lq * 4;
#pragma unroll
      for (int fb = 0; fb < 4; ++fb) {
        const int gc = col0 + wn * 64 + fb * 16 + li;
#pragma unroll
        for (int r = 0; r < 4; ++r)
          Cf[(size_t)(gr + r) * N + gc] = acc[fa][fb][r];
      }
    }
  }
}

// ---------------- Flash attention: global-LPT items, slot stores, lean VALU ----
// 48 items per (b,h): splits for qi>=16 (halves, 17..32 tiles) -> deterministic
// slot stores (part0 -> row t, part1 -> row t-2048; no atomics, no memset);
// wholes for qi<16 -> in-register normalize, direct bf16 store.
// Item table strictly size-sorted (LPT): size-32 items (qi31 halves AND qi15
// whole) first. Per-XCD decode interleaves the 3 (b,h) groups so all big
// items dispatch before any small one: wl = bid>>3; grp = xcd*3 + wl%3;
// e = g_items[wl/3]. Encoding: e = qi | part<<5 | split<<6.
// Inner loop: 3-deep LDS, counted vmcnt(4), one s_barrier/tile, swapped 32x32
// QK^T (first MFMA uses persistent zero C), compile-time-split causal mask
// (wave-uniform branch), v_perm packing, l row-sums on the MFMA pipe.

__device__ const uint8_t g_items[48] = {
  95,127,15, 94,126, 93,125,14, 92,124, 91,123,13, 90,122, 89,121,12, 88,120,
  87,119,11, 86,118, 85,117,10, 84,116, 83,115,9, 82,114, 81,113,8, 80,112,
  7,6,5,4,3,2,1,0};

__global__ __launch_bounds__(256) void attn(
    const unsigned short* __restrict__ qkv,   // [B][T][3C] (V slice unused)
    const unsigned short* __restrict__ vT,    // [B*NH][HS][T]
    float* __restrict__ Oacc,                 // [MTOK][NC] fp32 slot space
    float* __restrict__ lacc,                 // [B*NH][NT]  fp32 slot space
    unsigned short* __restrict__ aob) {       // [MTOK][NC] bf16 out (direct rows)
  __shared__ unsigned short Ks[3][64 * 64];
  __shared__ unsigned short Vts[3][64 * 64];

  const int tid = threadIdx.x;
  const int wave = tid >> 6;
  const int lane = tid & 63;
  const int l31 = lane & 31;
  const int lh = lane >> 5;
  const int sw = l31 & 7;                     // XOR-swizzle key for frag reads

  // ---- work decode: global LPT per XCD, groups interleaved ----
  const int bid = (int)blockIdx.x;            // 1152 = 8 XCD * 144
  const int xcd = bid & 7;
  const int wl = bid >> 3;                    // 0..143, dispatch-ordered
  const int grp = xcd * 3 + wl % 3;           // b*12+h (24 groups, 3 per XCD)
  const int e = (int)g_items[wl / 3];         // size-sorted rank
  const int qi = e & 31;
  const int part = (e >> 5) & 1;
  const int split = e >> 6;
  const int nt = 2 * qi + 2;
  int tauS, tauE;
  if (split) { if (part) { tauS = nt >> 1; tauE = nt; } else { tauS = 0; tauE = nt >> 1; } }
  else       { tauS = 0; tauE = nt; }
  const int b = grp / 12;
  const int h = grp - b * 12;
  const int q0 = qi * 128;
  const int bh = grp;

  const size_t baseQ = (size_t)b * NT * C3 + (size_t)h * HS;
  const size_t baseK = baseQ + NC;
  const unsigned short* kq = qkv + baseK;
  const unsigned short* vbase = vT + (size_t)bh * HS * NT;

  const int qw = q0 + wave * 32;              // wave's first q row
  const int qtok = qw + l31;                  // this lane's q token

  // Q B-fragments (pre-scaled via waT): lane holds Q[q=qw+l31][ks*16+lh*8..+7]
  bf16x8 bq[4];
#pragma unroll
  for (int ks = 0; ks < 4; ++ks)
    bq[ks] = *reinterpret_cast<const bf16x8*>(
        qkv + baseQ + (size_t)(qw + l31) * C3 + ks * 16 + lh * 8);

  // all-ones B fragment for l row-sums on the MFMA pipe
  bf16x8 vones;
#pragma unroll
  for (int i = 0; i < 8; ++i) vones[i] = (__bf16)1.0f;

  f32x16 o0 = {}, o1 = {}, la = {};
  const f32x16 zf = {};            // persistent zero C-operand (LICM'd movs)

  // ---- gload staging geometry: per wave, 2 calls x 8 rows for K and V ----
  // DMA writes linear (wave-uniform LDS base + lane*16B); the XOR swizzle is
  // applied on the per-lane GLOBAL address instead: LDS[R][c] = G[R][c^(R&7)].
  const int grow = lane >> 3;               // row within 8-row group
  const int gch = (lane & 7) ^ grow;        // pre-swizzled 16B chunk
  const int wr0 = wave * 8;                 // uniform row bases
  const int wr1 = wave * 8 + 32;

#define STAGE(TAU, BUFI)                                                        \
  do {                                                                          \
    const int t0s_ = (TAU) * 64;                                                \
    gload_lds16(kq + (size_t)(t0s_ + wr0 + grow) * C3 + gch * 8,                \
                &Ks[BUFI][wr0 * 64]);                                           \
    gload_lds16(kq + (size_t)(t0s_ + wr1 + grow) * C3 + gch * 8,                \
                &Ks[BUFI][wr1 * 64]);                                           \
    gload_lds16(vbase + (size_t)(wr0 + grow) * NT + t0s_ + gch * 8,             \
                &Vts[BUFI][wr0 * 64]);                                          \
    gload_lds16(vbase + (size_t)(wr1 + grow) * NT + t0s_ + gch * 8,             \
                &Vts[BUFI][wr1 * 64]);                                          \
  } while (0)

// exp + pack + permlane-swap one 32-k block (16 S^T regs) into pa[2*KBLK+s].
// DOMASK is a LITERAL 0/1 (code selected by a wave-uniform branch at the call
// site) -> no per-lane predication on clean tiles.
#define EXP_PACK(ST, KBLK, DOMASK)                                             \
  do {                                                                         \
    const int kb_ = t0 + (KBLK) * 32 + 4 * lh;                                 \
    float p_[16];                                                              \
    _Pragma("unroll") for (int r = 0; r < 16; ++r) {                           \
      float v_ = (ST)[r];                                                      \
      if (DOMASK) {                                                            \
        const int kt_ = kb_ + (r & 3) + 8 * (r >> 2);                          \
        if (kt_ > qtok) v_ = -INFINITY;                                        \
      }                                                                        \
      p_[r] = __builtin_amdgcn_exp2f(v_);                                      \
    }                                                                          \
    _Pragma("unroll") for (int s = 0; s < 2; ++s) {                            \
      uint32_t a_ = pack_bf2(p_[8 * s + 0], p_[8 * s + 1]);                    \
      uint32_t b_ = pack_bf2(p_[8 * s + 2], p_[8 * s + 3]);                    \
      uint32_t c_ = pack_bf2(p_[8 * s + 4], p_[8 * s + 5]);                    \
      uint32_t d_ = pack_bf2(p_[8 * s + 6], p_[8 * s + 7]);                    \
      asm("v_permlane32_swap_b32 %0, %1" : "+v"(a_), "+v"(c_));                \
      asm("v_permlane32_swap_b32 %0, %1" : "+v"(b_), "+v"(d_));                \
      union { uint32_t u[4]; bf16x8 v8; } pu_;                                 \
      pu_.u[0] = a_; pu_.u[1] = b_; pu_.u[2] = c_; pu_.u[3] = d_;              \
      pa[2 * (KBLK) + s] = pu_.v8;                                             \
    }                                                                          \
  } while (0)

// one PV k-step (16 k-tokens): l += P.1 ; O += P V  (V B-frag rows = d)
#define PV_STEP(KS)                                                            \
  do {                                                                         \
    const int off_ = ((((KS) * 2 + lh) ^ sw) << 3);                            \
    const bf16x8 bv0_ =                                                        \
        *reinterpret_cast<const bf16x8*>(Vc + (size_t)l31 * 64 + off_);        \
    const bf16x8 bv1_ =                                                        \
        *reinterpret_cast<const bf16x8*>(Vc + (size_t)(32 + l31) * 64 + off_); \
    la = mfma32(pa[KS], vones, la);                                            \
    o0 = mfma32(pa[KS], bv0_, o0);                                             \
    o1 = mfma32(pa[KS], bv1_, o1);                                             \
  } while (0)

  // prologue: 2 tiles in flight (tauE - tauS >= 2 always)
  STAGE(tauS, 0);
  STAGE(tauS + 1, 1);

  int cur = 0;
  for (int tau = tauS; tau < tauE; ++tau) {
    const int t0 = tau * 64;
    // counted drain: tile tau's 4 loads landed; tau+1's stay in flight.
    if (tau + 1 < tauE) asm volatile("s_waitcnt vmcnt(4)" ::: "memory");
    else                asm volatile("s_waitcnt vmcnt(0)" ::: "memory");
    __builtin_amdgcn_s_barrier();          // publish buf[cur] to all waves
    __builtin_amdgcn_sched_barrier(0);     // no hoisting across the barrier
    if (tau + 2 < tauE) {
      int nb = cur + 2; if (nb >= 3) nb -= 3;   // overwrites buf read at tau-1
      STAGE(tau + 2, nb);
    }

    const unsigned short* Kc = Ks[cur];
    const unsigned short* Vc = Vts[cur];

    if (t0 <= qw + 31) {                 // wave has live q-rows in this tile
      const bool act1 = (t0 + 32 <= qw + 31);   // k-block 1 live?
      const bool m0 = (t0 + 31 > qw);           // k-block 0 needs masking?
      const bool m1 = (t0 + 63 > qw);           // k-block 1 needs masking?

      // ---- S^T = K Q^T: A = K rows (k-tokens), B = Q cols ----
      f32x16 st0, st1;
      __builtin_amdgcn_s_setprio(1);
      {
        const bf16x8 ka0 = *reinterpret_cast<const bf16x8*>(
            Kc + (size_t)l31 * 64 + ((lh ^ sw) << 3));
        st0 = mfma32(ka0, bq[0], zf);
      }
#pragma unroll
      for (int ks = 1; ks < 4; ++ks) {
        const bf16x8 ka = *reinterpret_cast<const bf16x8*>(
            Kc + (size_t)l31 * 64 + (((ks * 2 + lh) ^ sw) << 3));
        st0 = mfma32(ka, bq[ks], st0);
      }
      if (act1) {
        {
          const bf16x8 ka0 = *reinterpret_cast<const bf16x8*>(
              Kc + (size_t)(32 + l31) * 64 + ((lh ^ sw) << 3));
          st1 = mfma32(ka0, bq[0], zf);
        }
#pragma unroll
        for (int ks = 1; ks < 4; ++ks) {
          const bf16x8 ka = *reinterpret_cast<const bf16x8*>(
              Kc + (size_t)(32 + l31) * 64 + (((ks * 2 + lh) ^ sw) << 3));
          st1 = mfma32(ka, bq[ks], st1);
        }
      }
      __builtin_amdgcn_s_setprio(0);

      // ---- exp + pack + swap -> pa[4]; mask code only on diagonal tiles ----
      bf16x8 pa[4];
      if (m0) EXP_PACK(st0, 0, 1); else EXP_PACK(st0, 0, 0);
      if (act1) {
        if (m1) EXP_PACK(st1, 1, 1); else EXP_PACK(st1, 1, 0);
      }

      // ---- O += P V ; l += P . ones (MFMA pipe) ----
      __builtin_amdgcn_s_setprio(1);
      PV_STEP(0); PV_STEP(1);
      if (act1) { PV_STEP(2); PV_STEP(3); }
      __builtin_amdgcn_s_setprio(0);
    }
    ++cur; if (cur == 3) cur = 0;
  }
#undef STAGE
#undef EXP_PACK
#undef PV_STEP

  // ---- epilogue ----
  // o0/o1 C-layout: col = l31 (d), reg r -> q = qw + (r&3)+8*(r>>2)+4*lh.
  // la[r] = row-sum, uniform across l31.
  if (split) {
    // deterministic slot store (no atomics): slot row = q (part0) or q-2048.
    float* lrow = lacc + (size_t)bh * NT;
#pragma unroll
    for (int r = 0; r < 16; ++r) {
      const int q = qw + (r & 3) + 8 * (r >> 2) + 4 * lh;
      const int srow = part ? (q - 2048) : q;
      if (l31 == 0) lrow[srow] = la[r];
      float* orow = Oacc + ((size_t)b * NT + srow) * NC + h * HS;
      orow[l31] = o0[r];
      orow[32 + l31] = o1[r];
    }
  } else {
#pragma unroll
    for (int r = 0; r < 16; ++r) {
      const int q = qw + (r & 3) + 8 * (r >> 2) + 4 * lh;
      const float inv = 1.0f / la[r];
      unsigned short* orow = aob + ((size_t)b * NT + q) * NC + h * HS;
      orow[l31] = bft(o0[r] * inv);
      orow[32 + l31] = bft(o1[r] * inv);
    }
  }
}

// ---------------- finalize: merge 2 slots, aob = bf16((O0+O1)/(l0+l1)), t >= 2048 ----
__global__ __launch_bounds__(256) void finalize(
    const float* __restrict__ Oacc, const float* __restrict__ lacc,
    unsigned short* __restrict__ aob) {
  const int idx4 = (blockIdx.x * 256 + threadIdx.x);
  if (idx4 >= NB * (NT / 2) * NC / 4) return;
  const int idx = idx4 * 4;
  const int rowp = idx / NC;          // 0 .. NB*2048-1
  const int cc = idx - rowp * NC;
  const int b = rowp >> 11;           // NT/2 = 2048
  const int t = (NT / 2) + (rowp & 2047);
  const int h = cc >> 6;
  const float* lrow = lacc + (size_t)(b * NHEAD + h) * NT;
  const float inv = 1.0f / (lrow[t] + lrow[t - 2048]);
  const size_t base0 = ((size_t)b * NT + t) * NC + cc;
  const size_t base1 = ((size_t)b * NT + (t - 2048)) * NC + cc;
  const float4 v0 = *reinterpret_cast<const float4*>(Oacc + base0);
  const float4 v1 = *reinterpret_cast<const float4*>(Oacc + base1);
  ushort4 o;
  o.x = bft((v0.x + v1.x) * inv); o.y = bft((v0.y + v1.y) * inv);
  o.z = bft((v0.z + v1.z) * inv); o.w = bft((v0.w + v1.w) * inv);
  *reinterpret_cast<ushort4*>(aob + base0) = o;
}

// ---------------- launch ----------------
extern "C" void kernel_launch(void* const* d_in, const int* in_sizes, int n_in,
                              void* d_out, int out_size, void* d_ws, size_t ws_size,
                              hipStream_t stream) {
  const float* x = (const float*)d_in[0];       // [B,T,C]
  const float* w_attn = (const float*)d_in[1];  // [C, 3C]
  const float* w_proj = (const float*)d_in[2];  // [C, C]
  float* outp = (float*)d_out;

  // ws layout (Oacc aliases xb/waT, which die after gemm1; every slot row of
  // Oacc/lacc is written before finalize reads it -> no memset needed):
  char* w = (char*)d_ws;
  float* Oacc = (float*)w;
  unsigned short* xb = (unsigned short*)w;                       // aliases Oacc (pre-attn)
  unsigned short* waT = xb + (size_t)MTOK * NC;                  // aliases Oacc tail
  float* lacc = Oacc + (size_t)MTOK * NC;
  unsigned short* qkvb = (unsigned short*)(lacc + (size_t)NB * NHEAD * NT);
  unsigned short* aob  = qkvb + (size_t)MTOK * C3;               // [MTOK][NC] bf16
  unsigned short* vTb  = aob + (size_t)MTOK * NC;                // [B*NH][HS][T]
  unsigned short* wpT  = vTb + (size_t)MTOK * NC;                // [NC][NC] bf16

  // prep: 576 transpose tiles + x-cast blocks
  prep<<<576 + MTOK * NC / 4 / 256, 256, 0, stream>>>(x, w_attn, w_proj, xb, waT, wpT);

  // qkv = x @ w_attn (Q rows of waT pre-scaled); V blocks write vTb directly
  gemm128<1><<<dim3(C3 / 128, MTOK / 128), 256, 0, stream>>>(xb, waT, qkvb, vTb, MTOK, C3, NC);

  // attention: 1152 global-LPT items, deterministic slot stores (no atomics/memset)
  attn<<<1152, 256, 0, stream>>>(qkvb, vTb, Oacc, lacc, aob);

  // merge slots + normalize rows t >= 2048 -> bf16 aob
  finalize<<<(NB * (NT / 2) * NC / 4 + 255) / 256, 256, 0, stream>>>(Oacc, lacc, aob);

  // out = att_out @ w_proj -> fp32 d_out
  gemm128<0><<<dim3(NC / 128, MTOK / 128), 256, 0, stream>>>(aob, wpT, outp, nullptr, MTOK, NC, NC);
}